// Round 1
// baseline (1000.347 us; speedup 1.0000x reference)
//
#include <hip/hip_runtime.h>
#include <stdint.h>

// SoftKMeans fused: dist = cdist(x, centroids), soft = softmax(-dist), loss = sum(soft*sq)/B
// x: (16,8192,256) fp32  -> M = 131072 rows, D = 256
// centroids: (1024,256) fp32 -> K = 1024 cols
// out: soft (131072*1024 fp32) ++ loss (1 fp32)
//
// Strategy: bf16 MFMA (16x16x32) for x.c^T; x2/c2 kept fp32 so only the cross
// term carries bf16 error. Each 512-thread block owns 64 rows x 1024 cols of
// logits fully in registers (8 waves = 2 row-groups x 4 col-groups, 128 acc
// VGPRs/lane), then does fused softmax + loss + store. Centroids pre-converted
// to bf16 in ws (512KB, L2-resident).

typedef float  f32x4  __attribute__((ext_vector_type(4)));
typedef short  s16x8  __attribute__((ext_vector_type(8)));
typedef unsigned int u32x4 __attribute__((ext_vector_type(4)));
typedef unsigned int u32x2 __attribute__((ext_vector_type(2)));

#define DD 256
#define KC 1024
#define MTOT 131072
#define LOSS_IDX ((size_t)MTOT * (size_t)KC)

__device__ __forceinline__ unsigned short bf16_rne(float f) {
  unsigned int u = __builtin_bit_cast(unsigned int, f);
  u += 0x7fffu + ((u >> 16) & 1u);   // round-to-nearest-even (no NaNs in data)
  return (unsigned short)(u >> 16);
}

// prep: centroids fp32 -> bf16 into ws, c2 = ||c||^2 fp32, zero the loss slot.
__global__ void skm_prep(const float* __restrict__ cent,
                         unsigned short* __restrict__ cbf,
                         float* __restrict__ c2,
                         float* __restrict__ out) {
  const int c = blockIdx.x;       // 1024 blocks, one centroid each
  const int t = threadIdx.x;      // 64 threads: 4 floats each
  const float* p = cent + (size_t)c * DD + t * 4;
  float v0 = p[0], v1 = p[1], v2 = p[2], v3 = p[3];
  u32x2 pack;
  pack.x = (unsigned int)bf16_rne(v0) | ((unsigned int)bf16_rne(v1) << 16);
  pack.y = (unsigned int)bf16_rne(v2) | ((unsigned int)bf16_rne(v3) << 16);
  *(u32x2*)(cbf + (size_t)c * DD + t * 4) = pack;
  float s = v0*v0 + v1*v1 + v2*v2 + v3*v3;
  #pragma unroll
  for (int off = 32; off >= 1; off >>= 1) s += __shfl_xor(s, off, 64);
  if (t == 0) c2[c] = s;
  if (c == 0 && t == 0) out[LOSS_IDX] = 0.0f;   // harness poisons d_out each call
}

__global__ __launch_bounds__(512, 2) void skm_main(
    const float* __restrict__ x,
    const unsigned short* __restrict__ cbf,
    const float* __restrict__ c2,
    float* __restrict__ out) {
  __shared__ float s_x2[64];
  __shared__ float s_r1[64][4];
  __shared__ float s_r2[64][4];
  __shared__ float s_row[64];

  const int tid  = threadIdx.x;
  const int wave = tid >> 6;
  const int lane = tid & 63;
  const int quad = lane >> 4;      // 0..3
  const int l16  = lane & 15;      // 0..15
  const int rg   = wave & 1;       // row group: 2 x 32 rows
  const int cg   = wave >> 1;      // col group: 4 x 256 cols
  const int rowbase = blockIdx.x * 64 + rg * 32;
  const int colbase = cg * 256;

  // acc[tr][tc][rr]: row = rg*32 + tr*16 + quad*4 + rr, col = colbase + tc*16 + l16
  f32x4 acc[2][16];
  #pragma unroll
  for (int tr = 0; tr < 2; ++tr)
    #pragma unroll
    for (int tc = 0; tc < 16; ++tc)
      acc[tr][tc] = (f32x4){0.f, 0.f, 0.f, 0.f};

  float x2p0 = 0.f, x2p1 = 0.f;

  // A-frag layout (verified): A[m = lane&15][k = quad*8 + j], j contiguous.
  const float* pa0 = x + (size_t)(rowbase + l16) * DD + quad * 8;
  const float* pa1 = pa0 + (size_t)16 * DD;
  // B-frag: lane holds cent[col = colbase + tc*16 + l16][k = quad*8 + j] (contiguous bf16 -> 16B load)
  const unsigned short* pb0 = cbf + (size_t)(colbase + l16) * DD + quad * 8;

  #pragma unroll 2
  for (int kk = 0; kk < 8; ++kk) {     // D reduction, 32 per step
    const int ko = kk * 32;
    s16x8 afr0, afr1;
    {
      f32x4 a0 = *(const f32x4*)(pa0 + ko);
      f32x4 a1 = *(const f32x4*)(pa0 + ko + 4);
      x2p0 += a0[0]*a0[0] + a0[1]*a0[1] + a0[2]*a0[2] + a0[3]*a0[3]
            + a1[0]*a1[0] + a1[1]*a1[1] + a1[2]*a1[2] + a1[3]*a1[3];
      afr0[0] = (short)bf16_rne(a0[0]); afr0[1] = (short)bf16_rne(a0[1]);
      afr0[2] = (short)bf16_rne(a0[2]); afr0[3] = (short)bf16_rne(a0[3]);
      afr0[4] = (short)bf16_rne(a1[0]); afr0[5] = (short)bf16_rne(a1[1]);
      afr0[6] = (short)bf16_rne(a1[2]); afr0[7] = (short)bf16_rne(a1[3]);
    }
    {
      f32x4 a0 = *(const f32x4*)(pa1 + ko);
      f32x4 a1 = *(const f32x4*)(pa1 + ko + 4);
      x2p1 += a0[0]*a0[0] + a0[1]*a0[1] + a0[2]*a0[2] + a0[3]*a0[3]
            + a1[0]*a1[0] + a1[1]*a1[1] + a1[2]*a1[2] + a1[3]*a1[3];
      afr1[0] = (short)bf16_rne(a0[0]); afr1[1] = (short)bf16_rne(a0[1]);
      afr1[2] = (short)bf16_rne(a0[2]); afr1[3] = (short)bf16_rne(a0[3]);
      afr1[4] = (short)bf16_rne(a1[0]); afr1[5] = (short)bf16_rne(a1[1]);
      afr1[6] = (short)bf16_rne(a1[2]); afr1[7] = (short)bf16_rne(a1[3]);
    }
    #pragma unroll
    for (int tc = 0; tc < 16; ++tc) {
      u32x4 braw = *(const u32x4*)(pb0 + (size_t)tc * 16 * DD + ko);
      s16x8 bfr = __builtin_bit_cast(s16x8, braw);
      acc[0][tc] = __builtin_amdgcn_mfma_f32_16x16x32_bf16(afr0, bfr, acc[0][tc], 0, 0, 0);
      acc[1][tc] = __builtin_amdgcn_mfma_f32_16x16x32_bf16(afr1, bfr, acc[1][tc], 0, 0, 0);
    }
  }

  // x2: lane has partial for row l16 over k = quad*8+j (+32Z); reduce across quads.
  x2p0 += __shfl_xor(x2p0, 16, 64); x2p0 += __shfl_xor(x2p0, 32, 64);
  x2p1 += __shfl_xor(x2p1, 16, 64); x2p1 += __shfl_xor(x2p1, 32, 64);
  if (cg == 0 && quad == 0) {        // all col groups computed identical values
    s_x2[rg * 32 + l16]      = x2p0;
    s_x2[rg * 32 + 16 + l16] = x2p1;
  }
  __syncthreads();

  float c2v[16];
  #pragma unroll
  for (int tc = 0; tc < 16; ++tc) c2v[tc] = c2[colbase + tc * 16 + l16];

  const int r0 = rg * 32 + quad * 4;   // row-in-wg for (tr=0, rr=0)
  float x2r[2][4];
  #pragma unroll
  for (int tr = 0; tr < 2; ++tr)
    #pragma unroll
    for (int rr = 0; rr < 4; ++rr)
      x2r[tr][rr] = s_x2[r0 + tr * 16 + rr];

  // sq -> dist (overwrite acc), track per-row min dist over this wave's cols
  float mn[2][4];
  #pragma unroll
  for (int tr = 0; tr < 2; ++tr)
    #pragma unroll
    for (int rr = 0; rr < 4; ++rr) mn[tr][rr] = 3.4e38f;

  #pragma unroll
  for (int tr = 0; tr < 2; ++tr)
    #pragma unroll
    for (int tc = 0; tc < 16; ++tc) {
      f32x4 a = acc[tr][tc];
      #pragma unroll
      for (int rr = 0; rr < 4; ++rr) {
        float s = x2r[tr][rr] + c2v[tc] - 2.0f * a[rr];
        s = fmaxf(s, 0.0f);
        float d = sqrtf(s);
        a[rr] = d;
        mn[tr][rr] = fminf(mn[tr][rr], d);
      }
      acc[tr][tc] = a;
    }

  // reduce min across the 16 lanes of each quad (cols), then across col groups via LDS
  #pragma unroll
  for (int tr = 0; tr < 2; ++tr)
    #pragma unroll
    for (int rr = 0; rr < 4; ++rr)
      #pragma unroll
      for (int off = 1; off <= 8; off <<= 1)
        mn[tr][rr] = fminf(mn[tr][rr], __shfl_xor(mn[tr][rr], off, 64));
  if (l16 == 0) {
    #pragma unroll
    for (int tr = 0; tr < 2; ++tr)
      #pragma unroll
      for (int rr = 0; rr < 4; ++rr)
        s_r1[r0 + tr * 16 + rr][cg] = mn[tr][rr];
  }
  __syncthreads();
  if (tid < 64) {
    float m = fminf(fminf(s_r1[tid][0], s_r1[tid][1]), fminf(s_r1[tid][2], s_r1[tid][3]));
    s_row[tid] = m;
  }
  __syncthreads();

  float dmn[2][4];
  #pragma unroll
  for (int tr = 0; tr < 2; ++tr)
    #pragma unroll
    for (int rr = 0; rr < 4; ++rr)
      dmn[tr][rr] = s_row[r0 + tr * 16 + rr];

  // exp pass: e = exp(dmin - d) (max-subtracted logits), partial denom + loss numerator
  float sme[2][4], lse[2][4];
  #pragma unroll
  for (int tr = 0; tr < 2; ++tr)
    #pragma unroll
    for (int rr = 0; rr < 4; ++rr) { sme[tr][rr] = 0.f; lse[tr][rr] = 0.f; }

  #pragma unroll
  for (int tr = 0; tr < 2; ++tr)
    #pragma unroll
    for (int tc = 0; tc < 16; ++tc) {
      f32x4 a = acc[tr][tc];
      #pragma unroll
      for (int rr = 0; rr < 4; ++rr) {
        float d = a[rr];
        float e = __expf(dmn[tr][rr] - d);
        lse[tr][rr] += e * d * d;       // soft*sq numerator (sq = d^2)
        sme[tr][rr] += e;
        a[rr] = e;
      }
      acc[tr][tc] = a;
    }

  #pragma unroll
  for (int tr = 0; tr < 2; ++tr)
    #pragma unroll
    for (int rr = 0; rr < 4; ++rr)
      #pragma unroll
      for (int off = 1; off <= 8; off <<= 1) {
        sme[tr][rr] += __shfl_xor(sme[tr][rr], off, 64);
        lse[tr][rr] += __shfl_xor(lse[tr][rr], off, 64);
      }
  if (l16 == 0) {
    #pragma unroll
    for (int tr = 0; tr < 2; ++tr)
      #pragma unroll
      for (int rr = 0; rr < 4; ++rr) {
        s_r1[r0 + tr * 16 + rr][cg] = sme[tr][rr];
        s_r2[r0 + tr * 16 + rr][cg] = lse[tr][rr];
      }
  }
  __syncthreads();
  if (tid < 64) {
    float den = s_r1[tid][0] + s_r1[tid][1] + s_r1[tid][2] + s_r1[tid][3];
    float num = s_r2[tid][0] + s_r2[tid][1] + s_r2[tid][2] + s_r2[tid][3];
    float r = 1.0f / den;
    s_row[tid] = r;
    float lv = num * r;                 // per-row sum(soft*sq)
    #pragma unroll
    for (int off = 1; off <= 32; off <<= 1) lv += __shfl_xor(lv, off, 64);
    if (tid == 0) atomicAdd(out + LOSS_IDX, lv * (1.0f / 16.0f));
  }
  __syncthreads();

  float rdv[2][4];
  #pragma unroll
  for (int tr = 0; tr < 2; ++tr)
    #pragma unroll
    for (int rr = 0; rr < 4; ++rr)
      rdv[tr][rr] = s_row[r0 + tr * 16 + rr];

  // store soft = e * (1/den); 16 lanes of a quad write 64B contiguous per (tr,rr,tc)
  #pragma unroll
  for (int tr = 0; tr < 2; ++tr)
    #pragma unroll
    for (int rr = 0; rr < 4; ++rr) {
      size_t base = ((size_t)(blockIdx.x * 64 + rg * 32 + tr * 16 + quad * 4 + rr)) * KC
                    + colbase + l16;
      float r = rdv[tr][rr];
      #pragma unroll
      for (int tc = 0; tc < 16; ++tc)
        out[base + tc * 16] = acc[tr][tc][rr] * r;
    }
}

extern "C" void kernel_launch(void* const* d_in, const int* in_sizes, int n_in,
                              void* d_out, int out_size, void* d_ws, size_t ws_size,
                              hipStream_t stream) {
  const float* x    = (const float*)d_in[0];
  const float* cent = (const float*)d_in[1];
  float* out = (float*)d_out;
  // ws layout: bf16 centroids (1024*256*2 = 512KB) | c2 (1024 fp32)
  unsigned short* cbf = (unsigned short*)d_ws;
  float* c2 = (float*)((char*)d_ws + (size_t)KC * DD * sizeof(unsigned short));

  skm_prep<<<KC, 64, 0, stream>>>(cent, cbf, c2, out);
  skm_main<<<MTOT / 64, 512, 0, stream>>>(x, cbf, c2, out);
}